// Round 10
// baseline (244.170 us; speedup 1.0000x reference)
//
#include <hip/hip_runtime.h>

#define N_NODES 50000
#define N_PAD 50048          // 782 * 64
#define N_EDGES 800000
#define IN_F 96
#define NDW 48               // dwords per feature row (96 bf16)
#define OUT_F 128
#define KTOT 384             // GEMM K dim, k-major: K = k*96 + f

#define NB 782               // buckets of 64 rows: 782*64 = 50048 >= 50000
#define EPB 4096             // edges per block in bucket passes
#define NBLK ((N_EDGES + EPB - 1) / EPB)  // 196
#define NCH 16               // col chunks (col>>12), 50000>>12 = 12 max
#define NBIN (64 * NCH)      // 1024 sort bins per bucket

typedef __attribute__((ext_vector_type(8))) short bf16x8;
typedef __attribute__((ext_vector_type(4))) float f32x4;

__device__ __forceinline__ short f2bf(float x) {
  union { float f; unsigned u; } c;
  c.f = x;
  unsigned u = c.u;
  u = (u + 0x7FFFu + ((u >> 16) & 1u)) >> 16;  // round-to-nearest-even
  return (short)u;
}

__device__ __forceinline__ float bflo(unsigned u) {
  union { unsigned u; float f; } c;
  c.u = u << 16;
  return c.f;
}
__device__ __forceinline__ float bfhi(unsigned u) {
  union { unsigned u; float f; } c;
  c.u = u & 0xffff0000u;
  return c.f;
}

// ---------------- CSR build: bucketed 2-pass + per-bucket (row,colchunk) sort --

// passA: per-block histogram over NB buckets (bucket = row>>6)
__global__ __launch_bounds__(256) void passA_kernel(const int* __restrict__ rows,
                                                    int* __restrict__ hist) {
  __shared__ int h[NB];
  int B = blockIdx.x;
  for (int b = threadIdx.x; b < NB; b += 256) h[b] = 0;
  __syncthreads();
  int end = min((B + 1) * EPB, N_EDGES);
  for (int i = B * EPB + threadIdx.x; i < end; i += 256) atomicAdd(&h[rows[i] >> 6], 1);
  __syncthreads();
  for (int b = threadIdx.x; b < NB; b += 256) hist[b * NBLK + B] = h[b];
}

// scanA: per bucket b, exclusive scan over the NBLK block counts
__global__ __launch_bounds__(256) void scanA_kernel(const int* __restrict__ hist,
                                                    int* __restrict__ off,
                                                    int* __restrict__ total) {
  __shared__ int tmp[256];
  int b = blockIdx.x;
  int tid = threadIdx.x;
  int v = (tid < NBLK) ? hist[b * NBLK + tid] : 0;
  tmp[tid] = v;
  __syncthreads();
  for (int o = 1; o < 256; o <<= 1) {
    int t = (tid >= o) ? tmp[tid - o] : 0;
    __syncthreads();
    tmp[tid] += t;
    __syncthreads();
  }
  if (tid < NBLK) off[b * NBLK + tid] = tmp[tid] - v;
  if (tid == 255) total[b] = tmp[tid];
}

// scanB: exclusive scan of per-bucket totals -> bucket_start
__global__ __launch_bounds__(1024) void scanB_kernel(const int* __restrict__ total,
                                                     int* __restrict__ bucket_start) {
  __shared__ int tmp[1024];
  int tid = threadIdx.x;
  int v = (tid < NB) ? total[tid] : 0;
  tmp[tid] = v;
  __syncthreads();
  for (int o = 1; o < 1024; o <<= 1) {
    int t = (tid >= o) ? tmp[tid - o] : 0;
    __syncthreads();
    tmp[tid] += t;
    __syncthreads();
  }
  if (tid < NB) bucket_start[tid] = tmp[tid] - v;
  if (tid == 0) bucket_start[NB] = N_EDGES;
}

// passB: scatter records into bucket-grouped array; each (block,bucket) chunk is
// contiguous, so destination lines are written by one block in one window.
// rec.x = col (16b, N<65536) | local_row (6b) << 16 ; rec.y = fp32 val bits
__global__ __launch_bounds__(256) void passB_kernel(
    const int* __restrict__ rows, const int* __restrict__ cols,
    const float* __restrict__ vals, const int* __restrict__ off,
    const int* __restrict__ bucket_start, int2* __restrict__ recs) {
  __shared__ int cur[NB];
  int B = blockIdx.x;
  for (int b = threadIdx.x; b < NB; b += 256)
    cur[b] = bucket_start[b] + off[b * NBLK + B];
  __syncthreads();
  int end = min((B + 1) * EPB, N_EDGES);
  for (int i = B * EPB + threadIdx.x; i < end; i += 256) {
    int r = rows[i];
    int pos = atomicAdd(&cur[r >> 6], 1);
    recs[pos] = make_int2((cols[i] & 0xffff) | ((r & 63) << 16), __float_as_int(vals[i]));
  }
}

// bsort: one block per bucket; sort records by (local_row, col>>12) so each
// row's edges are processed in ascending col-chunk order (temporal L2 locality
// across concurrently-running waves). Emits row_start. recs2.x = col only.
__global__ __launch_bounds__(256) void bsort_kernel(
    const int* __restrict__ bucket_start, const int2* __restrict__ recs,
    int2* __restrict__ recs2, int* __restrict__ row_start) {
  __shared__ int hist[NBIN];
  __shared__ int gsum[256];
  int b = blockIdx.x;
  int tid = threadIdx.x;
#pragma unroll
  for (int j = 0; j < NBIN / 256; ++j) hist[tid + j * 256] = 0;
  __syncthreads();
  int s = bucket_start[b], e = bucket_start[b + 1];
  for (int i = s + tid; i < e; i += 256) {
    int rx = recs[i].x;
    int key = (((rx >> 16) & 63) << 4) | ((rx & 0xffff) >> 12);
    atomicAdd(&hist[key], 1);
  }
  __syncthreads();
  // exclusive scan of hist[NBIN]: per-thread serial over 4 bins + Hillis over 256
  int base = tid * (NBIN / 256);
  int lsum = 0;
#pragma unroll
  for (int j = 0; j < NBIN / 256; ++j) lsum += hist[base + j];
  gsum[tid] = lsum;
  __syncthreads();
  for (int o = 1; o < 256; o <<= 1) {
    int t = (tid >= o) ? gsum[tid - o] : 0;
    __syncthreads();
    gsum[tid] += t;
    __syncthreads();
  }
  int acc = gsum[tid] - lsum;  // exclusive over groups
#pragma unroll
  for (int j = 0; j < NBIN / 256; ++j) {
    int t = hist[base + j];
    hist[base + j] = acc;
    acc += t;
  }
  __syncthreads();
  if (tid < 64) {
    int r = b * 64 + tid;
    if (r < N_NODES) row_start[r] = s + hist[tid << 4];
  }
  if (b == 0 && tid == 0) row_start[N_NODES] = N_EDGES;
  __syncthreads();
  for (int i = s + tid; i < e; i += 256) {
    int2 rec = recs[i];
    int key = (((rec.x >> 16) & 63) << 4) | ((rec.x & 0xffff) >> 12);
    int pos = s + atomicAdd(&hist[key], 1);
    recs2[pos] = make_int2(rec.x & 0xffff, rec.y);
  }
}

// ---------------- dtype prep ----------------

__global__ void convert_x_kernel(const float* __restrict__ x, unsigned* __restrict__ xb) {
  int i = blockIdx.x * blockDim.x + threadIdx.x;  // dword index, 2 feats each
  if (i < N_NODES * NDW) {
    float2 v = reinterpret_cast<const float2*>(x)[i];
    xb[i] = (unsigned)(unsigned short)f2bf(v.x) | ((unsigned)(unsigned short)f2bf(v.y) << 16);
  }
}

// Wb[o][k*96+f] = bf16(W[o][f*4+k])  (k-major K axis to match A = [xb|T1b|T2b|T3b])
__global__ void convert_w_kernel(const float* __restrict__ W, short* __restrict__ Wb) {
  int i = blockIdx.x * blockDim.x + threadIdx.x;
  if (i < OUT_F * KTOT) {
    int o = i / KTOT;
    int r = i - o * KTOT;
    int k = r / IN_F;
    int f = r - k * IN_F;
    Wb[i] = f2bf(W[o * KTOT + f * 4 + k]);
  }
}

// ---------------- SpMM, 4-edge-parallel wave, all-bf16 (unchanged r7 design) --
// r[row,:] = alpha * sum_e val[e]*vb[col[e],:] + beta * prevb[row,:]
// wave = 1 row; 64 lanes = 4 edge-slots x 16 lanes; lane loads 3 dwords/edge

__global__ __launch_bounds__(256) void spmm_cheb_kernel(
    const int* __restrict__ row_start, const int2* __restrict__ recs,
    const short* __restrict__ vb,     // bf16 [N][96] gather source
    const short* __restrict__ prevb,  // bf16 [N][96]
    float alpha, float beta,
    unsigned* __restrict__ yb) {      // bf16 [N][96] out as dwords
  int row = blockIdx.x * 4 + (threadIdx.x >> 6);
  if (row >= N_NODES) return;
  int lane = threadIdx.x & 63;
  int eslot = lane >> 4;  // 0..3
  int lid = lane & 15;    // 0..15
  int s = row_start[row];
  int e = row_start[row + 1];

  float acc[6];
#pragma unroll
  for (int i = 0; i < 6; ++i) acc[i] = 0.f;

#pragma unroll 2
  for (int base = s; base < e; base += 4) {
    int idx = base + eslot;
    int c = 0;
    float val = 0.f;
    if (idx < e) {
      int2 rec = recs[idx];
      c = rec.x;
      val = __int_as_float(rec.y);
    }
    const unsigned* srcd = reinterpret_cast<const unsigned*>(vb + (size_t)c * IN_F);
#pragma unroll
    for (int it = 0; it < 3; ++it) {
      unsigned dv = srcd[it * 16 + lid];
      acc[2 * it] += val * bflo(dv);
      acc[2 * it + 1] += val * bfhi(dv);
    }
  }

#pragma unroll
  for (int i = 0; i < 6; ++i) {
    acc[i] += __shfl_xor(acc[i], 16);
    acc[i] += __shfl_xor(acc[i], 32);
  }

  if (eslot < 3) {
    int d = eslot * 16 + lid;  // dword index 0..47, feats 2d, 2d+1
    unsigned pv = reinterpret_cast<const unsigned*>(prevb + (size_t)row * IN_F)[d];
    float r0 = alpha * acc[2 * eslot] + beta * bflo(pv);
    float r1 = alpha * acc[2 * eslot + 1] + beta * bfhi(pv);
    yb[(size_t)row * NDW + d] =
        (unsigned)(unsigned short)f2bf(r0) | ((unsigned)(unsigned short)f2bf(r1) << 16);
  }
}

// ---------------- MFMA GEMM: out[n][o] = bias[o] + sum_K A[n][K] * Wb[o][K] ----
// A = concat_K of 4 bf16 [N][96] segments. Block: 4 waves, 64 nodes x 128 outs.

__global__ __launch_bounds__(256) void gemm_mfma_kernel(
    const short* __restrict__ s0, const short* __restrict__ s1,
    const short* __restrict__ s2, const short* __restrict__ s3,
    const short* __restrict__ Bm,  // [128][384] bf16, k-major K
    const float* __restrict__ bias,
    float* __restrict__ out) {
  int tid = threadIdx.x;
  int wave = tid >> 6;
  int lane = tid & 63;
  int n0 = blockIdx.x * 64;
  int o0 = wave * 32;
  int lr = lane & 15;        // row-in-A-frag / col-in-B-frag
  int lk = (lane >> 4) * 8;  // k offset within frag

  f32x4 acc[4][2];
#pragma unroll
  for (int m = 0; m < 4; ++m)
#pragma unroll
    for (int nn = 0; nn < 2; ++nn) acc[m][nn] = (f32x4){0.f, 0.f, 0.f, 0.f};

  const short* segs[4] = {s0, s1, s2, s3};
  const short* bptr = Bm + (size_t)(o0 + lr) * KTOT + lk;

#pragma unroll
  for (int seg = 0; seg < 4; ++seg) {
    const short* aseg = segs[seg] + (size_t)(n0 + lr) * IN_F + lk;
#pragma unroll
    for (int t = 0; t < 3; ++t) {
      int kt = seg * 3 + t;
      bf16x8 a[4], b[2];
#pragma unroll
      for (int m = 0; m < 4; ++m)
        a[m] = *reinterpret_cast<const bf16x8*>(aseg + (size_t)m * 16 * IN_F + t * 32);
#pragma unroll
      for (int nn = 0; nn < 2; ++nn)
        b[nn] = *reinterpret_cast<const bf16x8*>(bptr + (size_t)nn * 16 * KTOT + kt * 32);
#pragma unroll
      for (int m = 0; m < 4; ++m)
#pragma unroll
        for (int nn = 0; nn < 2; ++nn)
          acc[m][nn] = __builtin_amdgcn_mfma_f32_16x16x32_bf16(a[m], b[nn], acc[m][nn], 0, 0, 0);
    }
  }

  int orow = (lane >> 4) * 4;  // C/D: col = lane&15, row = (lane>>4)*4 + reg
#pragma unroll
  for (int m = 0; m < 4; ++m) {
#pragma unroll
    for (int nn = 0; nn < 2; ++nn) {
      int oc = o0 + nn * 16 + lr;
      float bv = bias[oc];
#pragma unroll
      for (int j = 0; j < 4; ++j) {
        int n = n0 + m * 16 + orow + j;
        if (n < N_NODES) out[(size_t)n * OUT_F + oc] = acc[m][nn][j] + bv;
      }
    }
  }
}

// ---------------- launch ----------------

extern "C" void kernel_launch(void* const* d_in, const int* in_sizes, int n_in,
                              void* d_out, int out_size, void* d_ws, size_t ws_size,
                              hipStream_t stream) {
  const float* x = (const float*)d_in[0];
  const int* lap_rows = (const int*)d_in[1];
  const int* lap_cols = (const int*)d_in[2];
  const float* lap_vals = (const float*)d_in[3];
  const float* W = (const float*)d_in[4];
  const float* b = (const float*)d_in[5];
  float* out = (float*)d_out;

  char* ws = (char*)d_ws;
  short* xb = (short*)ws;            ws += (size_t)N_NODES * IN_F * 2;  // 9.6 MB
  short* T1b = (short*)ws;           ws += (size_t)N_NODES * IN_F * 2;
  short* T2b = (short*)ws;           ws += (size_t)N_NODES * IN_F * 2;
  short* T3b = (short*)ws;           ws += (size_t)N_NODES * IN_F * 2;
  short* Wb = (short*)ws;            ws += (size_t)OUT_F * KTOT * 2;    // 96 KB
  int* hist = (int*)ws;              ws += (size_t)NB * NBLK * 4;       // 613 KB
  int* off = (int*)ws;               ws += (size_t)NB * NBLK * 4;
  int* total = (int*)ws;             ws += (size_t)NB * 4;
  int* bucket_start = (int*)ws;      ws += (size_t)(NB + 2) * 4;
  int* row_start = (int*)ws;         ws += (size_t)(N_NODES + 8) * 4;
  ws = (char*)(((size_t)ws + 15) & ~(size_t)15);
  int2* recs = (int2*)ws;            ws += (size_t)N_EDGES * 8;         // 6.4 MB
  int2* recs2 = (int2*)ws;           ws += (size_t)N_EDGES * 8;         // 6.4 MB

  passA_kernel<<<NBLK, 256, 0, stream>>>(lap_rows, hist);
  scanA_kernel<<<NB, 256, 0, stream>>>(hist, off, total);
  scanB_kernel<<<1, 1024, 0, stream>>>(total, bucket_start);
  passB_kernel<<<NBLK, 256, 0, stream>>>(lap_rows, lap_cols, lap_vals, off, bucket_start,
                                         recs);
  bsort_kernel<<<NB, 256, 0, stream>>>(bucket_start, recs, recs2, row_start);

  convert_x_kernel<<<(N_NODES * NDW + 255) / 256, 256, 0, stream>>>(x, (unsigned*)xb);
  convert_w_kernel<<<(OUT_F * KTOT + 255) / 256, 256, 0, stream>>>(W, Wb);

  int sb = (N_NODES + 3) / 4;  // 1 row per wave, 4 waves per block
  spmm_cheb_kernel<<<sb, 256, 0, stream>>>(row_start, recs2, xb, xb, 1.f, 0.f,
                                           (unsigned*)T1b);
  spmm_cheb_kernel<<<sb, 256, 0, stream>>>(row_start, recs2, T1b, xb, 2.f, -1.f,
                                           (unsigned*)T2b);
  spmm_cheb_kernel<<<sb, 256, 0, stream>>>(row_start, recs2, T2b, T1b, 2.f, -1.f,
                                           (unsigned*)T3b);

  gemm_mfma_kernel<<<N_PAD / 64, 256, 0, stream>>>(xb, T1b, T2b, T3b, Wb, b, out);
}

// Round 11
// 232.141 us; speedup vs baseline: 1.0518x; 1.0518x over previous
//
#include <hip/hip_runtime.h>

#define N_NODES 50000
#define N_PAD 50048          // 782 * 64
#define N_EDGES 800000
#define IN_F 96
#define NDW 48               // dwords per feature row (96 bf16)
#define OUT_F 128
#define KTOT 384             // GEMM K dim, k-major: K = k*96 + f

#define NB 782               // buckets of 64 rows: 782*64 = 50048 >= 50000
#define EPB 4096             // edges per block in bucket passes
#define NBLK ((N_EDGES + EPB - 1) / EPB)  // 196

#define SPMM_BLOCKS 4096     // persistent grid-stride SpMM

typedef __attribute__((ext_vector_type(8))) short bf16x8;
typedef __attribute__((ext_vector_type(4))) float f32x4;

__device__ __forceinline__ short f2bf(float x) {
  union { float f; unsigned u; } c;
  c.f = x;
  unsigned u = c.u;
  u = (u + 0x7FFFu + ((u >> 16) & 1u)) >> 16;  // round-to-nearest-even
  return (short)u;
}

__device__ __forceinline__ float bflo(unsigned u) {
  union { unsigned u; float f; } c;
  c.u = u << 16;
  return c.f;
}
__device__ __forceinline__ float bfhi(unsigned u) {
  union { unsigned u; float f; } c;
  c.u = u & 0xffff0000u;
  return c.f;
}

// ---------------- CSR build: bucketed 2-pass + per-bucket row sort ----------

// passA: per-block histogram over NB buckets (bucket = row>>6)
__global__ __launch_bounds__(256) void passA_kernel(const int* __restrict__ rows,
                                                    int* __restrict__ hist) {
  __shared__ int h[NB];
  int B = blockIdx.x;
  for (int b = threadIdx.x; b < NB; b += 256) h[b] = 0;
  __syncthreads();
  int end = min((B + 1) * EPB, N_EDGES);
  for (int i = B * EPB + threadIdx.x; i < end; i += 256) atomicAdd(&h[rows[i] >> 6], 1);
  __syncthreads();
  for (int b = threadIdx.x; b < NB; b += 256) hist[b * NBLK + B] = h[b];
}

// scanA: per bucket b, exclusive scan over the NBLK block counts
__global__ __launch_bounds__(256) void scanA_kernel(const int* __restrict__ hist,
                                                    int* __restrict__ off,
                                                    int* __restrict__ total) {
  __shared__ int tmp[256];
  int b = blockIdx.x;
  int tid = threadIdx.x;
  int v = (tid < NBLK) ? hist[b * NBLK + tid] : 0;
  tmp[tid] = v;
  __syncthreads();
  for (int o = 1; o < 256; o <<= 1) {
    int t = (tid >= o) ? tmp[tid - o] : 0;
    __syncthreads();
    tmp[tid] += t;
    __syncthreads();
  }
  if (tid < NBLK) off[b * NBLK + tid] = tmp[tid] - v;
  if (tid == 255) total[b] = tmp[tid];
}

// scanB: exclusive scan of per-bucket totals -> bucket_start
__global__ __launch_bounds__(1024) void scanB_kernel(const int* __restrict__ total,
                                                     int* __restrict__ bucket_start) {
  __shared__ int tmp[1024];
  int tid = threadIdx.x;
  int v = (tid < NB) ? total[tid] : 0;
  tmp[tid] = v;
  __syncthreads();
  for (int o = 1; o < 1024; o <<= 1) {
    int t = (tid >= o) ? tmp[tid - o] : 0;
    __syncthreads();
    tmp[tid] += t;
    __syncthreads();
  }
  if (tid < NB) bucket_start[tid] = tmp[tid] - v;
  if (tid == 0) bucket_start[NB] = N_EDGES;
}

// passB: scatter records into bucket-grouped array; each (block,bucket) chunk is
// contiguous, so destination lines are written by one block in one window.
// rec.x = col (16b, N<65536) | local_row (6b) << 16 ; rec.y = fp32 val bits
__global__ __launch_bounds__(256) void passB_kernel(
    const int* __restrict__ rows, const int* __restrict__ cols,
    const float* __restrict__ vals, const int* __restrict__ off,
    const int* __restrict__ bucket_start, int2* __restrict__ recs) {
  __shared__ int cur[NB];
  int B = blockIdx.x;
  for (int b = threadIdx.x; b < NB; b += 256)
    cur[b] = bucket_start[b] + off[b * NBLK + B];
  __syncthreads();
  int end = min((B + 1) * EPB, N_EDGES);
  for (int i = B * EPB + threadIdx.x; i < end; i += 256) {
    int r = rows[i];
    int pos = atomicAdd(&cur[r >> 6], 1);
    recs[pos] = make_int2((cols[i] & 0xffff) | ((r & 63) << 16), __float_as_int(vals[i]));
  }
}

// bsort: one block per bucket; row-sort the bucket's records (local 8KB region)
// and emit row_start. recs2.x = col only.
__global__ __launch_bounds__(256) void bsort_kernel(
    const int* __restrict__ bucket_start, const int2* __restrict__ recs,
    int2* __restrict__ recs2, int* __restrict__ row_start) {
  __shared__ int hist[64], excl[64], cur[64];
  int b = blockIdx.x;
  int tid = threadIdx.x;
  if (tid < 64) hist[tid] = 0;
  __syncthreads();
  int s = bucket_start[b], e = bucket_start[b + 1];
  for (int i = s + tid; i < e; i += 256) atomicAdd(&hist[(recs[i].x >> 16) & 63], 1);
  __syncthreads();
  if (tid == 0) {
    int acc = 0;
    for (int j = 0; j < 64; ++j) {
      excl[j] = acc;
      acc += hist[j];
    }
  }
  __syncthreads();
  if (tid < 64) {
    cur[tid] = excl[tid];
    int r = b * 64 + tid;
    if (r < N_NODES) row_start[r] = s + excl[tid];
  }
  if (b == 0 && tid == 0) row_start[N_NODES] = N_EDGES;
  __syncthreads();
  for (int i = s + tid; i < e; i += 256) {
    int2 rec = recs[i];
    int lr = (rec.x >> 16) & 63;
    int pos = s + atomicAdd(&cur[lr], 1);
    recs2[pos] = make_int2(rec.x & 0xffff, rec.y);
  }
}

// ---------------- dtype prep (fused x + W) ----------------

#define NXD (N_NODES * NDW)  // 2400000 dwords of x

__global__ void convert_xw_kernel(const float* __restrict__ x, unsigned* __restrict__ xb,
                                  const float* __restrict__ W, short* __restrict__ Wb) {
  int i = blockIdx.x * blockDim.x + threadIdx.x;
  if (i < NXD) {
    float2 v = reinterpret_cast<const float2*>(x)[i];
    xb[i] = (unsigned)(unsigned short)f2bf(v.x) | ((unsigned)(unsigned short)f2bf(v.y) << 16);
  } else if (i < NXD + OUT_F * KTOT) {
    int j = i - NXD;
    int o = j / KTOT;
    int r = j - o * KTOT;
    int k = r / IN_F;
    int f = r - k * IN_F;
    Wb[j] = f2bf(W[o * KTOT + f * 4 + k]);  // k-major K axis
  }
}

// ---------------- SpMM: persistent waves, 4-edge-parallel, rec prefetch -------
// r[row,:] = alpha * sum_e val[e]*vb[col[e],:] + beta * prevb[row,:]
// wave handles rows wid, wid+16384, ...; 64 lanes = 4 edge-slots x 16 lanes;
// lane loads 3 dwords/edge; next iteration's rec is prefetched before gathering.

__global__ __launch_bounds__(256) void spmm_cheb_kernel(
    const int* __restrict__ row_start, const int2* __restrict__ recs,
    const short* __restrict__ vb,     // bf16 [N][96] gather source
    const short* __restrict__ prevb,  // bf16 [N][96]
    float alpha, float beta,
    unsigned* __restrict__ yb) {      // bf16 [N][96] out as dwords
  int wid = blockIdx.x * 4 + (threadIdx.x >> 6);
  int lane = threadIdx.x & 63;
  int eslot = lane >> 4;  // 0..3
  int lid = lane & 15;    // 0..15
  const int stride = SPMM_BLOCKS * 4;

  for (int row = wid; row < N_NODES; row += stride) {
    int s = row_start[row];
    int e = row_start[row + 1];

    float acc[6];
#pragma unroll
    for (int i = 0; i < 6; ++i) acc[i] = 0.f;

    int idx = s + eslot;
    int2 rec = (idx < e) ? recs[idx] : make_int2(0, 0);  // val bits 0 -> 0.0f

    for (int base = s; base < e; base += 4) {
      int2 cur = rec;
      int nidx = base + 4 + eslot;
      rec = (nidx < e) ? recs[nidx] : make_int2(0, 0);
      int c = cur.x;
      float val = __int_as_float(cur.y);
      const unsigned* srcd = reinterpret_cast<const unsigned*>(vb + (size_t)c * IN_F);
      unsigned d0 = srcd[lid];
      unsigned d1 = srcd[16 + lid];
      unsigned d2 = srcd[32 + lid];
      acc[0] += val * bflo(d0);
      acc[1] += val * bfhi(d0);
      acc[2] += val * bflo(d1);
      acc[3] += val * bfhi(d1);
      acc[4] += val * bflo(d2);
      acc[5] += val * bfhi(d2);
    }

#pragma unroll
    for (int i = 0; i < 6; ++i) {
      acc[i] += __shfl_xor(acc[i], 16);
      acc[i] += __shfl_xor(acc[i], 32);
    }

    if (eslot < 3) {
      int d = eslot * 16 + lid;  // dword index 0..47, feats 2d, 2d+1
      unsigned pv = reinterpret_cast<const unsigned*>(prevb + (size_t)row * IN_F)[d];
      float r0 = alpha * acc[2 * eslot] + beta * bflo(pv);
      float r1 = alpha * acc[2 * eslot + 1] + beta * bfhi(pv);
      yb[(size_t)row * NDW + d] =
          (unsigned)(unsigned short)f2bf(r0) | ((unsigned)(unsigned short)f2bf(r1) << 16);
    }
  }
}

// ---------------- MFMA GEMM: out[n][o] = bias[o] + sum_K A[n][K] * Wb[o][K] ----
// A = concat_K of 4 bf16 [N][96] segments. Block: 4 waves, 64 nodes x 128 outs.

__global__ __launch_bounds__(256) void gemm_mfma_kernel(
    const short* __restrict__ s0, const short* __restrict__ s1,
    const short* __restrict__ s2, const short* __restrict__ s3,
    const short* __restrict__ Bm,  // [128][384] bf16, k-major K
    const float* __restrict__ bias,
    float* __restrict__ out) {
  int tid = threadIdx.x;
  int wave = tid >> 6;
  int lane = tid & 63;
  int n0 = blockIdx.x * 64;
  int o0 = wave * 32;
  int lr = lane & 15;        // row-in-A-frag / col-in-B-frag
  int lk = (lane >> 4) * 8;  // k offset within frag

  f32x4 acc[4][2];
#pragma unroll
  for (int m = 0; m < 4; ++m)
#pragma unroll
    for (int nn = 0; nn < 2; ++nn) acc[m][nn] = (f32x4){0.f, 0.f, 0.f, 0.f};

  const short* segs[4] = {s0, s1, s2, s3};
  const short* bptr = Bm + (size_t)(o0 + lr) * KTOT + lk;

#pragma unroll
  for (int seg = 0; seg < 4; ++seg) {
    const short* aseg = segs[seg] + (size_t)(n0 + lr) * IN_F + lk;
#pragma unroll
    for (int t = 0; t < 3; ++t) {
      int kt = seg * 3 + t;
      bf16x8 a[4], b[2];
#pragma unroll
      for (int m = 0; m < 4; ++m)
        a[m] = *reinterpret_cast<const bf16x8*>(aseg + (size_t)m * 16 * IN_F + t * 32);
#pragma unroll
      for (int nn = 0; nn < 2; ++nn)
        b[nn] = *reinterpret_cast<const bf16x8*>(bptr + (size_t)nn * 16 * KTOT + kt * 32);
#pragma unroll
      for (int m = 0; m < 4; ++m)
#pragma unroll
        for (int nn = 0; nn < 2; ++nn)
          acc[m][nn] = __builtin_amdgcn_mfma_f32_16x16x32_bf16(a[m], b[nn], acc[m][nn], 0, 0, 0);
    }
  }

  int orow = (lane >> 4) * 4;  // C/D: col = lane&15, row = (lane>>4)*4 + reg
#pragma unroll
  for (int m = 0; m < 4; ++m) {
#pragma unroll
    for (int nn = 0; nn < 2; ++nn) {
      int oc = o0 + nn * 16 + lr;
      float bv = bias[oc];
#pragma unroll
      for (int j = 0; j < 4; ++j) {
        int n = n0 + m * 16 + orow + j;
        if (n < N_NODES) out[(size_t)n * OUT_F + oc] = acc[m][nn][j] + bv;
      }
    }
  }
}

// ---------------- launch ----------------

extern "C" void kernel_launch(void* const* d_in, const int* in_sizes, int n_in,
                              void* d_out, int out_size, void* d_ws, size_t ws_size,
                              hipStream_t stream) {
  const float* x = (const float*)d_in[0];
  const int* lap_rows = (const int*)d_in[1];
  const int* lap_cols = (const int*)d_in[2];
  const float* lap_vals = (const float*)d_in[3];
  const float* W = (const float*)d_in[4];
  const float* b = (const float*)d_in[5];
  float* out = (float*)d_out;

  char* ws = (char*)d_ws;
  short* xb = (short*)ws;            ws += (size_t)N_NODES * IN_F * 2;  // 9.6 MB
  short* T1b = (short*)ws;           ws += (size_t)N_NODES * IN_F * 2;
  short* T2b = (short*)ws;           ws += (size_t)N_NODES * IN_F * 2;
  short* T3b = (short*)ws;           ws += (size_t)N_NODES * IN_F * 2;
  short* Wb = (short*)ws;            ws += (size_t)OUT_F * KTOT * 2;    // 96 KB
  int* hist = (int*)ws;              ws += (size_t)NB * NBLK * 4;       // 613 KB
  int* off = (int*)ws;               ws += (size_t)NB * NBLK * 4;
  int* total = (int*)ws;             ws += (size_t)NB * 4;
  int* bucket_start = (int*)ws;      ws += (size_t)(NB + 2) * 4;
  int* row_start = (int*)ws;         ws += (size_t)(N_NODES + 8) * 4;
  ws = (char*)(((size_t)ws + 15) & ~(size_t)15);
  int2* recs = (int2*)ws;            ws += (size_t)N_EDGES * 8;         // 6.4 MB
  int2* recs2 = (int2*)ws;           ws += (size_t)N_EDGES * 8;         // 6.4 MB

  passA_kernel<<<NBLK, 256, 0, stream>>>(lap_rows, hist);
  scanA_kernel<<<NB, 256, 0, stream>>>(hist, off, total);
  scanB_kernel<<<1, 1024, 0, stream>>>(total, bucket_start);
  passB_kernel<<<NBLK, 256, 0, stream>>>(lap_rows, lap_cols, lap_vals, off, bucket_start,
                                         recs);
  bsort_kernel<<<NB, 256, 0, stream>>>(bucket_start, recs, recs2, row_start);

  convert_xw_kernel<<<(NXD + OUT_F * KTOT + 255) / 256, 256, 0, stream>>>(x, (unsigned*)xb,
                                                                          W, Wb);

  spmm_cheb_kernel<<<SPMM_BLOCKS, 256, 0, stream>>>(row_start, recs2, xb, xb, 1.f, 0.f,
                                                    (unsigned*)T1b);
  spmm_cheb_kernel<<<SPMM_BLOCKS, 256, 0, stream>>>(row_start, recs2, T1b, xb, 2.f, -1.f,
                                                    (unsigned*)T2b);
  spmm_cheb_kernel<<<SPMM_BLOCKS, 256, 0, stream>>>(row_start, recs2, T2b, T1b, 2.f, -1.f,
                                                    (unsigned*)T3b);

  gemm_mfma_kernel<<<N_PAD / 64, 256, 0, stream>>>(xb, T1b, T2b, T3b, Wb, b, out);
}

// Round 12
// 231.216 us; speedup vs baseline: 1.0560x; 1.0040x over previous
//
#include <hip/hip_runtime.h>

#define N_NODES 50000
#define N_PAD 50048          // 782 * 64
#define N_EDGES 800000
#define IN_F 96
#define NDW 48               // dwords per feature row (96 bf16)
#define OUT_F 128
#define KTOT 384             // GEMM K dim, k-major: K = k*96 + f

#define NB 782               // buckets of 64 rows: 782*64 = 50048 >= 50000
#define EPB 4096             // edges per block in bucket passes
#define NBLK ((N_EDGES + EPB - 1) / EPB)  // 196

#define SPMM_BLOCKS 4096     // persistent grid-stride SpMM

typedef __attribute__((ext_vector_type(8))) short bf16x8;
typedef __attribute__((ext_vector_type(4))) float f32x4;

__device__ __forceinline__ short f2bf(float x) {
  union { float f; unsigned u; } c;
  c.f = x;
  unsigned u = c.u;
  u = (u + 0x7FFFu + ((u >> 16) & 1u)) >> 16;  // round-to-nearest-even
  return (short)u;
}

__device__ __forceinline__ float bflo(unsigned u) {
  union { unsigned u; float f; } c;
  c.u = u << 16;
  return c.f;
}
__device__ __forceinline__ float bfhi(unsigned u) {
  union { unsigned u; float f; } c;
  c.u = u & 0xffff0000u;
  return c.f;
}

// ---------------- CSR build: bucketed 2-pass + per-bucket row sort ----------

// passA: per-block histogram over NB buckets (bucket = row>>6)
__global__ __launch_bounds__(256) void passA_kernel(const int* __restrict__ rows,
                                                    int* __restrict__ hist) {
  __shared__ int h[NB];
  int B = blockIdx.x;
  for (int b = threadIdx.x; b < NB; b += 256) h[b] = 0;
  __syncthreads();
  int end = min((B + 1) * EPB, N_EDGES);
  for (int i = B * EPB + threadIdx.x; i < end; i += 256) atomicAdd(&h[rows[i] >> 6], 1);
  __syncthreads();
  for (int b = threadIdx.x; b < NB; b += 256) hist[b * NBLK + B] = h[b];
}

// scanA: per bucket b, exclusive scan over the NBLK block counts
__global__ __launch_bounds__(256) void scanA_kernel(const int* __restrict__ hist,
                                                    int* __restrict__ off,
                                                    int* __restrict__ total) {
  __shared__ int tmp[256];
  int b = blockIdx.x;
  int tid = threadIdx.x;
  int v = (tid < NBLK) ? hist[b * NBLK + tid] : 0;
  tmp[tid] = v;
  __syncthreads();
  for (int o = 1; o < 256; o <<= 1) {
    int t = (tid >= o) ? tmp[tid - o] : 0;
    __syncthreads();
    tmp[tid] += t;
    __syncthreads();
  }
  if (tid < NBLK) off[b * NBLK + tid] = tmp[tid] - v;
  if (tid == 255) total[b] = tmp[tid];
}

// scanB: exclusive scan of per-bucket totals -> bucket_start
__global__ __launch_bounds__(1024) void scanB_kernel(const int* __restrict__ total,
                                                     int* __restrict__ bucket_start) {
  __shared__ int tmp[1024];
  int tid = threadIdx.x;
  int v = (tid < NB) ? total[tid] : 0;
  tmp[tid] = v;
  __syncthreads();
  for (int o = 1; o < 1024; o <<= 1) {
    int t = (tid >= o) ? tmp[tid - o] : 0;
    __syncthreads();
    tmp[tid] += t;
    __syncthreads();
  }
  if (tid < NB) bucket_start[tid] = tmp[tid] - v;
  if (tid == 0) bucket_start[NB] = N_EDGES;
}

// passB: scatter records into bucket-grouped array; each (block,bucket) chunk is
// contiguous, so destination lines are written by one block in one window.
// rec.x = col (16b, N<65536) | local_row (6b) << 16 ; rec.y = fp32 val bits
__global__ __launch_bounds__(256) void passB_kernel(
    const int* __restrict__ rows, const int* __restrict__ cols,
    const float* __restrict__ vals, const int* __restrict__ off,
    const int* __restrict__ bucket_start, int2* __restrict__ recs) {
  __shared__ int cur[NB];
  int B = blockIdx.x;
  for (int b = threadIdx.x; b < NB; b += 256)
    cur[b] = bucket_start[b] + off[b * NBLK + B];
  __syncthreads();
  int end = min((B + 1) * EPB, N_EDGES);
  for (int i = B * EPB + threadIdx.x; i < end; i += 256) {
    int r = rows[i];
    int pos = atomicAdd(&cur[r >> 6], 1);
    recs[pos] = make_int2((cols[i] & 0xffff) | ((r & 63) << 16), __float_as_int(vals[i]));
  }
}

// bsort: one block per bucket; row-sort the bucket's records (local 8KB region)
// and emit row_start. recs2.x = col only.
__global__ __launch_bounds__(256) void bsort_kernel(
    const int* __restrict__ bucket_start, const int2* __restrict__ recs,
    int2* __restrict__ recs2, int* __restrict__ row_start) {
  __shared__ int hist[64], excl[64], cur[64];
  int b = blockIdx.x;
  int tid = threadIdx.x;
  if (tid < 64) hist[tid] = 0;
  __syncthreads();
  int s = bucket_start[b], e = bucket_start[b + 1];
  for (int i = s + tid; i < e; i += 256) atomicAdd(&hist[(recs[i].x >> 16) & 63], 1);
  __syncthreads();
  if (tid == 0) {
    int acc = 0;
    for (int j = 0; j < 64; ++j) {
      excl[j] = acc;
      acc += hist[j];
    }
  }
  __syncthreads();
  if (tid < 64) {
    cur[tid] = excl[tid];
    int r = b * 64 + tid;
    if (r < N_NODES) row_start[r] = s + excl[tid];
  }
  if (b == 0 && tid == 0) row_start[N_NODES] = N_EDGES;
  __syncthreads();
  for (int i = s + tid; i < e; i += 256) {
    int2 rec = recs[i];
    int lr = (rec.x >> 16) & 63;
    int pos = s + atomicAdd(&cur[lr], 1);
    recs2[pos] = make_int2(rec.x & 0xffff, rec.y);
  }
}

// ---------------- dtype prep (fused x + W) ----------------

#define NXD (N_NODES * NDW)  // 2400000 dwords of x

__global__ void convert_xw_kernel(const float* __restrict__ x, unsigned* __restrict__ xb,
                                  const float* __restrict__ W, short* __restrict__ Wb) {
  int i = blockIdx.x * blockDim.x + threadIdx.x;
  if (i < NXD) {
    float2 v = reinterpret_cast<const float2*>(x)[i];
    xb[i] = (unsigned)(unsigned short)f2bf(v.x) | ((unsigned)(unsigned short)f2bf(v.y) << 16);
  } else if (i < NXD + OUT_F * KTOT) {
    int j = i - NXD;
    int o = j / KTOT;
    int r = j - o * KTOT;
    int k = r / IN_F;
    int f = r - k * IN_F;
    Wb[j] = f2bf(W[o * KTOT + f * 4 + k]);  // k-major K axis
  }
}

// ---------------- SpMM: persistent waves, 8-edge-parallel, rec prefetch -------
// r[row,:] = alpha * sum_e val[e]*vb[col[e],:] + beta * prevb[row,:]
// wave handles rows wid, wid+16384, ...; 64 lanes = 8 edge-slots x 8 lanes;
// lane loads 3 uint2 (8B) per edge; next iteration's rec prefetched.

__global__ __launch_bounds__(256) void spmm_cheb_kernel(
    const int* __restrict__ row_start, const int2* __restrict__ recs,
    const short* __restrict__ vb,     // bf16 [N][96] gather source
    const short* __restrict__ prevb,  // bf16 [N][96]
    float alpha, float beta,
    unsigned* __restrict__ yb) {      // bf16 [N][96] out as dwords
  int wid = blockIdx.x * 4 + (threadIdx.x >> 6);
  int lane = threadIdx.x & 63;
  int eslot = lane >> 3;  // 0..7
  int lid = lane & 7;     // 0..7
  const int stride = SPMM_BLOCKS * 4;

  for (int row = wid; row < N_NODES; row += stride) {
    int s = row_start[row];
    int e = row_start[row + 1];

    float acc[12];
#pragma unroll
    for (int i = 0; i < 12; ++i) acc[i] = 0.f;

    int idx = s + eslot;
    int2 rec = (idx < e) ? recs[idx] : make_int2(0, 0);  // val bits 0 -> 0.0f

    for (int base = s; base < e; base += 8) {
      int2 cur = rec;
      int nidx = base + 8 + eslot;
      rec = (nidx < e) ? recs[nidx] : make_int2(0, 0);
      int c = cur.x;
      float val = __int_as_float(cur.y);
      // qword q = it*8 + lid covers dwords it*16 + 2*lid, +1
      const uint2* srcq = reinterpret_cast<const uint2*>(vb + (size_t)c * IN_F);
      uint2 q0 = srcq[lid];
      uint2 q1 = srcq[8 + lid];
      uint2 q2 = srcq[16 + lid];
      acc[0] += val * bflo(q0.x);
      acc[1] += val * bfhi(q0.x);
      acc[2] += val * bflo(q0.y);
      acc[3] += val * bfhi(q0.y);
      acc[4] += val * bflo(q1.x);
      acc[5] += val * bfhi(q1.x);
      acc[6] += val * bflo(q1.y);
      acc[7] += val * bfhi(q1.y);
      acc[8] += val * bflo(q2.x);
      acc[9] += val * bfhi(q2.x);
      acc[10] += val * bflo(q2.y);
      acc[11] += val * bfhi(q2.y);
    }

    // reduce over the 8 edge-slots (lane bits 3,4,5)
#pragma unroll
    for (int i = 0; i < 12; ++i) {
      acc[i] += __shfl_xor(acc[i], 8);
      acc[i] += __shfl_xor(acc[i], 16);
      acc[i] += __shfl_xor(acc[i], 32);
    }

    if (eslot < 6) {
      int it = eslot >> 1, j = eslot & 1;
      int d = it * 16 + 2 * lid + j;  // output dword 0..47 (feats 2d, 2d+1)
      unsigned pv = reinterpret_cast<const unsigned*>(prevb + (size_t)row * IN_F)[d];
      float r0 = alpha * acc[4 * it + 2 * j] + beta * bflo(pv);
      float r1 = alpha * acc[4 * it + 2 * j + 1] + beta * bfhi(pv);
      yb[(size_t)row * NDW + d] =
          (unsigned)(unsigned short)f2bf(r0) | ((unsigned)(unsigned short)f2bf(r1) << 16);
    }
  }
}

// ---------------- MFMA GEMM: out[n][o] = bias[o] + sum_K A[n][K] * Wb[o][K] ----
// A = concat_K of 4 bf16 [N][96] segments. Block: 4 waves, 64 nodes x 128 outs.

__global__ __launch_bounds__(256) void gemm_mfma_kernel(
    const short* __restrict__ s0, const short* __restrict__ s1,
    const short* __restrict__ s2, const short* __restrict__ s3,
    const short* __restrict__ Bm,  // [128][384] bf16, k-major K
    const float* __restrict__ bias,
    float* __restrict__ out) {
  int tid = threadIdx.x;
  int wave = tid >> 6;
  int lane = tid & 63;
  int n0 = blockIdx.x * 64;
  int o0 = wave * 32;
  int lr = lane & 15;        // row-in-A-frag / col-in-B-frag
  int lk = (lane >> 4) * 8;  // k offset within frag

  f32x4 acc[4][2];
#pragma unroll
  for (int m = 0; m < 4; ++m)
#pragma unroll
    for (int nn = 0; nn < 2; ++nn) acc[m][nn] = (f32x4){0.f, 0.f, 0.f, 0.f};

  const short* segs[4] = {s0, s1, s2, s3};
  const short* bptr = Bm + (size_t)(o0 + lr) * KTOT + lk;

#pragma unroll
  for (int seg = 0; seg < 4; ++seg) {
    const short* aseg = segs[seg] + (size_t)(n0 + lr) * IN_F + lk;
#pragma unroll
    for (int t = 0; t < 3; ++t) {
      int kt = seg * 3 + t;
      bf16x8 a[4], b[2];
#pragma unroll
      for (int m = 0; m < 4; ++m)
        a[m] = *reinterpret_cast<const bf16x8*>(aseg + (size_t)m * 16 * IN_F + t * 32);
#pragma unroll
      for (int nn = 0; nn < 2; ++nn)
        b[nn] = *reinterpret_cast<const bf16x8*>(bptr + (size_t)nn * 16 * KTOT + kt * 32);
#pragma unroll
      for (int m = 0; m < 4; ++m)
#pragma unroll
        for (int nn = 0; nn < 2; ++nn)
          acc[m][nn] = __builtin_amdgcn_mfma_f32_16x16x32_bf16(a[m], b[nn], acc[m][nn], 0, 0, 0);
    }
  }

  int orow = (lane >> 4) * 4;  // C/D: col = lane&15, row = (lane>>4)*4 + reg
#pragma unroll
  for (int m = 0; m < 4; ++m) {
#pragma unroll
    for (int nn = 0; nn < 2; ++nn) {
      int oc = o0 + nn * 16 + lr;
      float bv = bias[oc];
#pragma unroll
      for (int j = 0; j < 4; ++j) {
        int n = n0 + m * 16 + orow + j;
        if (n < N_NODES) out[(size_t)n * OUT_F + oc] = acc[m][nn][j] + bv;
      }
    }
  }
}

// ---------------- launch ----------------

extern "C" void kernel_launch(void* const* d_in, const int* in_sizes, int n_in,
                              void* d_out, int out_size, void* d_ws, size_t ws_size,
                              hipStream_t stream) {
  const float* x = (const float*)d_in[0];
  const int* lap_rows = (const int*)d_in[1];
  const int* lap_cols = (const int*)d_in[2];
  const float* lap_vals = (const float*)d_in[3];
  const float* W = (const float*)d_in[4];
  const float* b = (const float*)d_in[5];
  float* out = (float*)d_out;

  char* ws = (char*)d_ws;
  short* xb = (short*)ws;            ws += (size_t)N_NODES * IN_F * 2;  // 9.6 MB
  short* T1b = (short*)ws;           ws += (size_t)N_NODES * IN_F * 2;
  short* T2b = (short*)ws;           ws += (size_t)N_NODES * IN_F * 2;
  short* T3b = (short*)ws;           ws += (size_t)N_NODES * IN_F * 2;
  short* Wb = (short*)ws;            ws += (size_t)OUT_F * KTOT * 2;    // 96 KB
  int* hist = (int*)ws;              ws += (size_t)NB * NBLK * 4;       // 613 KB
  int* off = (int*)ws;               ws += (size_t)NB * NBLK * 4;
  int* total = (int*)ws;             ws += (size_t)NB * 4;
  int* bucket_start = (int*)ws;      ws += (size_t)(NB + 2) * 4;
  int* row_start = (int*)ws;         ws += (size_t)(N_NODES + 8) * 4;
  ws = (char*)(((size_t)ws + 15) & ~(size_t)15);
  int2* recs = (int2*)ws;            ws += (size_t)N_EDGES * 8;         // 6.4 MB
  int2* recs2 = (int2*)ws;           ws += (size_t)N_EDGES * 8;         // 6.4 MB

  passA_kernel<<<NBLK, 256, 0, stream>>>(lap_rows, hist);
  scanA_kernel<<<NB, 256, 0, stream>>>(hist, off, total);
  scanB_kernel<<<1, 1024, 0, stream>>>(total, bucket_start);
  passB_kernel<<<NBLK, 256, 0, stream>>>(lap_rows, lap_cols, lap_vals, off, bucket_start,
                                         recs);
  bsort_kernel<<<NB, 256, 0, stream>>>(bucket_start, recs, recs2, row_start);

  convert_xw_kernel<<<(NXD + OUT_F * KTOT + 255) / 256, 256, 0, stream>>>(x, (unsigned*)xb,
                                                                          W, Wb);

  spmm_cheb_kernel<<<SPMM_BLOCKS, 256, 0, stream>>>(row_start, recs2, xb, xb, 1.f, 0.f,
                                                    (unsigned*)T1b);
  spmm_cheb_kernel<<<SPMM_BLOCKS, 256, 0, stream>>>(row_start, recs2, T1b, xb, 2.f, -1.f,
                                                    (unsigned*)T2b);
  spmm_cheb_kernel<<<SPMM_BLOCKS, 256, 0, stream>>>(row_start, recs2, T2b, T1b, 2.f, -1.f,
                                                    (unsigned*)T3b);

  gemm_mfma_kernel<<<N_PAD / 64, 256, 0, stream>>>(xb, T1b, T2b, T3b, Wb, b, out);
}

// Round 13
// 230.604 us; speedup vs baseline: 1.0588x; 1.0027x over previous
//
#include <hip/hip_runtime.h>

#define N_NODES 50000
#define N_PAD 50048          // 782 * 64
#define N_EDGES 800000
#define IN_F 96
#define NDW 48               // dwords per feature row (96 bf16)
#define OUT_F 128
#define KTOT 384             // GEMM K dim, k-major: K = k*96 + f

#define NB 782               // buckets of 64 rows: 782*64 = 50048 >= 50000
#define EPB 4096             // edges per block in bucket passes
#define NBLK ((N_EDGES + EPB - 1) / EPB)  // 196

#define SPMM_BLOCKS 4096     // persistent grid-stride SpMM

typedef __attribute__((ext_vector_type(8))) short bf16x8;
typedef __attribute__((ext_vector_type(4))) float f32x4;

__device__ __forceinline__ short f2bf(float x) {
  union { float f; unsigned u; } c;
  c.f = x;
  unsigned u = c.u;
  u = (u + 0x7FFFu + ((u >> 16) & 1u)) >> 16;  // round-to-nearest-even
  return (short)u;
}

__device__ __forceinline__ float bflo(unsigned u) {
  union { unsigned u; float f; } c;
  c.u = u << 16;
  return c.f;
}
__device__ __forceinline__ float bfhi(unsigned u) {
  union { unsigned u; float f; } c;
  c.u = u & 0xffff0000u;
  return c.f;
}

// ---------------- CSR build: bucketed 2-pass + per-bucket row sort ----------

// passA: per-block histogram over NB buckets (bucket = row>>6)
__global__ __launch_bounds__(256) void passA_kernel(const int* __restrict__ rows,
                                                    int* __restrict__ hist) {
  __shared__ int h[NB];
  int B = blockIdx.x;
  for (int b = threadIdx.x; b < NB; b += 256) h[b] = 0;
  __syncthreads();
  int end = min((B + 1) * EPB, N_EDGES);
  for (int i = B * EPB + threadIdx.x; i < end; i += 256) atomicAdd(&h[rows[i] >> 6], 1);
  __syncthreads();
  for (int b = threadIdx.x; b < NB; b += 256) hist[b * NBLK + B] = h[b];
}

// scanA: per bucket b, exclusive scan over the NBLK block counts
__global__ __launch_bounds__(256) void scanA_kernel(const int* __restrict__ hist,
                                                    int* __restrict__ off,
                                                    int* __restrict__ total) {
  __shared__ int tmp[256];
  int b = blockIdx.x;
  int tid = threadIdx.x;
  int v = (tid < NBLK) ? hist[b * NBLK + tid] : 0;
  tmp[tid] = v;
  __syncthreads();
  for (int o = 1; o < 256; o <<= 1) {
    int t = (tid >= o) ? tmp[tid - o] : 0;
    __syncthreads();
    tmp[tid] += t;
    __syncthreads();
  }
  if (tid < NBLK) off[b * NBLK + tid] = tmp[tid] - v;
  if (tid == 255) total[b] = tmp[tid];
}

// scanB: exclusive scan of per-bucket totals -> bucket_start
__global__ __launch_bounds__(1024) void scanB_kernel(const int* __restrict__ total,
                                                     int* __restrict__ bucket_start) {
  __shared__ int tmp[1024];
  int tid = threadIdx.x;
  int v = (tid < NB) ? total[tid] : 0;
  tmp[tid] = v;
  __syncthreads();
  for (int o = 1; o < 1024; o <<= 1) {
    int t = (tid >= o) ? tmp[tid - o] : 0;
    __syncthreads();
    tmp[tid] += t;
    __syncthreads();
  }
  if (tid < NB) bucket_start[tid] = tmp[tid] - v;
  if (tid == 0) bucket_start[NB] = N_EDGES;
}

// passB: scatter records into bucket-grouped array; each (block,bucket) chunk is
// contiguous, so destination lines are written by one block in one window.
// rec.x = col (16b, N<65536) | local_row (6b) << 16 ; rec.y = fp32 val bits
__global__ __launch_bounds__(256) void passB_kernel(
    const int* __restrict__ rows, const int* __restrict__ cols,
    const float* __restrict__ vals, const int* __restrict__ off,
    const int* __restrict__ bucket_start, int2* __restrict__ recs) {
  __shared__ int cur[NB];
  int B = blockIdx.x;
  for (int b = threadIdx.x; b < NB; b += 256)
    cur[b] = bucket_start[b] + off[b * NBLK + B];
  __syncthreads();
  int end = min((B + 1) * EPB, N_EDGES);
  for (int i = B * EPB + threadIdx.x; i < end; i += 256) {
    int r = rows[i];
    int pos = atomicAdd(&cur[r >> 6], 1);
    recs[pos] = make_int2((cols[i] & 0xffff) | ((r & 63) << 16), __float_as_int(vals[i]));
  }
}

// bsort: one block per bucket; row-sort the bucket's records (local 8KB region)
// and emit row_start. recs2.x = col only.
__global__ __launch_bounds__(256) void bsort_kernel(
    const int* __restrict__ bucket_start, const int2* __restrict__ recs,
    int2* __restrict__ recs2, int* __restrict__ row_start) {
  __shared__ int hist[64], excl[64], cur[64];
  int b = blockIdx.x;
  int tid = threadIdx.x;
  if (tid < 64) hist[tid] = 0;
  __syncthreads();
  int s = bucket_start[b], e = bucket_start[b + 1];
  for (int i = s + tid; i < e; i += 256) atomicAdd(&hist[(recs[i].x >> 16) & 63], 1);
  __syncthreads();
  if (tid == 0) {
    int acc = 0;
    for (int j = 0; j < 64; ++j) {
      excl[j] = acc;
      acc += hist[j];
    }
  }
  __syncthreads();
  if (tid < 64) {
    cur[tid] = excl[tid];
    int r = b * 64 + tid;
    if (r < N_NODES) row_start[r] = s + excl[tid];
  }
  if (b == 0 && tid == 0) row_start[N_NODES] = N_EDGES;
  __syncthreads();
  for (int i = s + tid; i < e; i += 256) {
    int2 rec = recs[i];
    int lr = (rec.x >> 16) & 63;
    int pos = s + atomicAdd(&cur[lr], 1);
    recs2[pos] = make_int2(rec.x & 0xffff, rec.y);
  }
}

// ---------------- dtype prep (fused x + W) ----------------

#define NXD (N_NODES * NDW)  // 2400000 dwords of x

__global__ void convert_xw_kernel(const float* __restrict__ x, unsigned* __restrict__ xb,
                                  const float* __restrict__ W, short* __restrict__ Wb) {
  int i = blockIdx.x * blockDim.x + threadIdx.x;
  if (i < NXD) {
    float2 v = reinterpret_cast<const float2*>(x)[i];
    xb[i] = (unsigned)(unsigned short)f2bf(v.x) | ((unsigned)(unsigned short)f2bf(v.y) << 16);
  } else if (i < NXD + OUT_F * KTOT) {
    int j = i - NXD;
    int o = j / KTOT;
    int r = j - o * KTOT;
    int k = r / IN_F;
    int f = r - k * IN_F;
    Wb[j] = f2bf(W[o * KTOT + f * 4 + k]);  // k-major K axis
  }
}

// ---------------- SpMM: persistent waves, 8-edge-parallel, software-pipelined -
// r[row,:] = alpha * sum_e val[e]*vb[col[e],:] + beta * prevb[row,:]
// 64 lanes = 8 edge-slots x 8 lanes; lane loads 3 uint2 (8B) per edge.
// Two gather stages in flight: stage i+1 issued before stage i is consumed.

__global__ __launch_bounds__(256) void spmm_cheb_kernel(
    const int* __restrict__ row_start, const int2* __restrict__ recs,
    const short* __restrict__ vb,     // bf16 [N][96] gather source
    const short* __restrict__ prevb,  // bf16 [N][96]
    float alpha, float beta,
    unsigned* __restrict__ yb) {      // bf16 [N][96] out as dwords
  int wid = blockIdx.x * 4 + (threadIdx.x >> 6);
  int lane = threadIdx.x & 63;
  int eslot = lane >> 3;  // 0..7
  int lid = lane & 7;     // 0..7
  const int stride = SPMM_BLOCKS * 4;

  int it_ = eslot >> 1, j_ = eslot & 1;
  int dout = it_ * 16 + 2 * lid + j_;  // epilogue dword 0..47 (for eslot<6)

  for (int row = wid; row < N_NODES; row += stride) {
    int s = row_start[row];
    int e = row_start[row + 1];

    // hoist epilogue's prev load so it's in flight during the edge loop
    unsigned pv = 0;
    if (eslot < 6) pv = reinterpret_cast<const unsigned*>(prevb + (size_t)row * IN_F)[dout];

    float acc[12];
#pragma unroll
    for (int i = 0; i < 12; ++i) acc[i] = 0.f;

    // stage 0: rec + gathers issued
    int idx = s + eslot;
    int2 rec0 = (idx < e) ? recs[idx] : make_int2(0, 0);  // val bits 0 -> 0.0f
    const uint2* sq0 = reinterpret_cast<const uint2*>(vb + (size_t)rec0.x * IN_F);
    uint2 a0 = sq0[lid], a1 = sq0[8 + lid], a2 = sq0[16 + lid];

    int base = s;
    for (; base + 8 < e; base += 8) {
      // issue stage 1 before consuming stage 0
      int nidx = base + 8 + eslot;
      int2 rec1 = (nidx < e) ? recs[nidx] : make_int2(0, 0);
      const uint2* sq1 = reinterpret_cast<const uint2*>(vb + (size_t)rec1.x * IN_F);
      uint2 b0 = sq1[lid], b1 = sq1[8 + lid], b2 = sq1[16 + lid];

      float val = __int_as_float(rec0.y);
      acc[0] += val * bflo(a0.x);
      acc[1] += val * bfhi(a0.x);
      acc[2] += val * bflo(a0.y);
      acc[3] += val * bfhi(a0.y);
      acc[4] += val * bflo(a1.x);
      acc[5] += val * bfhi(a1.x);
      acc[6] += val * bflo(a1.y);
      acc[7] += val * bfhi(a1.y);
      acc[8] += val * bflo(a2.x);
      acc[9] += val * bfhi(a2.x);
      acc[10] += val * bflo(a2.y);
      acc[11] += val * bfhi(a2.y);

      rec0 = rec1;
      a0 = b0;
      a1 = b1;
      a2 = b2;
    }
    // drain last stage
    {
      float val = __int_as_float(rec0.y);
      acc[0] += val * bflo(a0.x);
      acc[1] += val * bfhi(a0.x);
      acc[2] += val * bflo(a0.y);
      acc[3] += val * bfhi(a0.y);
      acc[4] += val * bflo(a1.x);
      acc[5] += val * bfhi(a1.x);
      acc[6] += val * bflo(a1.y);
      acc[7] += val * bfhi(a1.y);
      acc[8] += val * bflo(a2.x);
      acc[9] += val * bfhi(a2.x);
      acc[10] += val * bflo(a2.y);
      acc[11] += val * bfhi(a2.y);
    }

    // reduce over the 8 edge-slots (lane bits 3,4,5)
#pragma unroll
    for (int i = 0; i < 12; ++i) {
      acc[i] += __shfl_xor(acc[i], 8);
      acc[i] += __shfl_xor(acc[i], 16);
      acc[i] += __shfl_xor(acc[i], 32);
    }

    if (eslot < 6) {
      float r0 = alpha * acc[4 * it_ + 2 * j_] + beta * bflo(pv);
      float r1 = alpha * acc[4 * it_ + 2 * j_ + 1] + beta * bfhi(pv);
      yb[(size_t)row * NDW + dout] =
          (unsigned)(unsigned short)f2bf(r0) | ((unsigned)(unsigned short)f2bf(r1) << 16);
    }
  }
}

// ---------------- MFMA GEMM: out[n][o] = bias[o] + sum_K A[n][K] * Wb[o][K] ----
// A = concat_K of 4 bf16 [N][96] segments. Block: 4 waves, 64 nodes x 128 outs.

__global__ __launch_bounds__(256) void gemm_mfma_kernel(
    const short* __restrict__ s0, const short* __restrict__ s1,
    const short* __restrict__ s2, const short* __restrict__ s3,
    const short* __restrict__ Bm,  // [128][384] bf16, k-major K
    const float* __restrict__ bias,
    float* __restrict__ out) {
  int tid = threadIdx.x;
  int wave = tid >> 6;
  int lane = tid & 63;
  int n0 = blockIdx.x * 64;
  int o0 = wave * 32;
  int lr = lane & 15;        // row-in-A-frag / col-in-B-frag
  int lk = (lane >> 4) * 8;  // k offset within frag

  f32x4 acc[4][2];
#pragma unroll
  for (int m = 0; m < 4; ++m)
#pragma unroll
    for (int nn = 0; nn < 2; ++nn) acc[m][nn] = (f32x4){0.f, 0.f, 0.f, 0.f};

  const short* segs[4] = {s0, s1, s2, s3};
  const short* bptr = Bm + (size_t)(o0 + lr) * KTOT + lk;

#pragma unroll
  for (int seg = 0; seg < 4; ++seg) {
    const short* aseg = segs[seg] + (size_t)(n0 + lr) * IN_F + lk;
#pragma unroll
    for (int t = 0; t < 3; ++t) {
      int kt = seg * 3 + t;
      bf16x8 a[4], b[2];
#pragma unroll
      for (int m = 0; m < 4; ++m)
        a[m] = *reinterpret_cast<const bf16x8*>(aseg + (size_t)m * 16 * IN_F + t * 32);
#pragma unroll
      for (int nn = 0; nn < 2; ++nn)
        b[nn] = *reinterpret_cast<const bf16x8*>(bptr + (size_t)nn * 16 * KTOT + kt * 32);
#pragma unroll
      for (int m = 0; m < 4; ++m)
#pragma unroll
        for (int nn = 0; nn < 2; ++nn)
          acc[m][nn] = __builtin_amdgcn_mfma_f32_16x16x32_bf16(a[m], b[nn], acc[m][nn], 0, 0, 0);
    }
  }

  int orow = (lane >> 4) * 4;  // C/D: col = lane&15, row = (lane>>4)*4 + reg
#pragma unroll
  for (int m = 0; m < 4; ++m) {
#pragma unroll
    for (int nn = 0; nn < 2; ++nn) {
      int oc = o0 + nn * 16 + lr;
      float bv = bias[oc];
#pragma unroll
      for (int j = 0; j < 4; ++j) {
        int n = n0 + m * 16 + orow + j;
        if (n < N_NODES) out[(size_t)n * OUT_F + oc] = acc[m][nn][j] + bv;
      }
    }
  }
}

// ---------------- launch ----------------

extern "C" void kernel_launch(void* const* d_in, const int* in_sizes, int n_in,
                              void* d_out, int out_size, void* d_ws, size_t ws_size,
                              hipStream_t stream) {
  const float* x = (const float*)d_in[0];
  const int* lap_rows = (const int*)d_in[1];
  const int* lap_cols = (const int*)d_in[2];
  const float* lap_vals = (const float*)d_in[3];
  const float* W = (const float*)d_in[4];
  const float* b = (const float*)d_in[5];
  float* out = (float*)d_out;

  char* ws = (char*)d_ws;
  short* xb = (short*)ws;            ws += (size_t)N_NODES * IN_F * 2;  // 9.6 MB
  short* T1b = (short*)ws;           ws += (size_t)N_NODES * IN_F * 2;
  short* T2b = (short*)ws;           ws += (size_t)N_NODES * IN_F * 2;
  short* T3b = (short*)ws;           ws += (size_t)N_NODES * IN_F * 2;
  short* Wb = (short*)ws;            ws += (size_t)OUT_F * KTOT * 2;    // 96 KB
  int* hist = (int*)ws;              ws += (size_t)NB * NBLK * 4;       // 613 KB
  int* off = (int*)ws;               ws += (size_t)NB * NBLK * 4;
  int* total = (int*)ws;             ws += (size_t)NB * 4;
  int* bucket_start = (int*)ws;      ws += (size_t)(NB + 2) * 4;
  int* row_start = (int*)ws;         ws += (size_t)(N_NODES + 8) * 4;
  ws = (char*)(((size_t)ws + 15) & ~(size_t)15);
  int2* recs = (int2*)ws;            ws += (size_t)N_EDGES * 8;         // 6.4 MB
  int2* recs2 = (int2*)ws;           ws += (size_t)N_EDGES * 8;         // 6.4 MB

  passA_kernel<<<NBLK, 256, 0, stream>>>(lap_rows, hist);
  scanA_kernel<<<NB, 256, 0, stream>>>(hist, off, total);
  scanB_kernel<<<1, 1024, 0, stream>>>(total, bucket_start);
  passB_kernel<<<NBLK, 256, 0, stream>>>(lap_rows, lap_cols, lap_vals, off, bucket_start,
                                         recs);
  bsort_kernel<<<NB, 256, 0, stream>>>(bucket_start, recs, recs2, row_start);

  convert_xw_kernel<<<(NXD + OUT_F * KTOT + 255) / 256, 256, 0, stream>>>(x, (unsigned*)xb,
                                                                          W, Wb);

  spmm_cheb_kernel<<<SPMM_BLOCKS, 256, 0, stream>>>(row_start, recs2, xb, xb, 1.f, 0.f,
                                                    (unsigned*)T1b);
  spmm_cheb_kernel<<<SPMM_BLOCKS, 256, 0, stream>>>(row_start, recs2, T1b, xb, 2.f, -1.f,
                                                    (unsigned*)T2b);
  spmm_cheb_kernel<<<SPMM_BLOCKS, 256, 0, stream>>>(row_start, recs2, T2b, T1b, 2.f, -1.f,
                                                    (unsigned*)T3b);

  gemm_mfma_kernel<<<N_PAD / 64, 256, 0, stream>>>(xb, T1b, T2b, T3b, Wb, b, out);
}